// Round 1
// baseline (3412.539 us; speedup 1.0000x reference)
//
#include <hip/hip_runtime.h>
#include <math.h>

#define NP 16384      // pixels per map (128*128)
#define CH 256        // channels (K)
#define WDIM 128
#define BM 128        // rows per block tile
#define BN 128        // cols per tile iteration
#define KC 32         // K chunk staged in LDS
#define LDX (BM + 4)  // padded LDS leading dim (floats)
#define NSPLIT 2
#define CPS (NP / NSPLIT)  // cols per split
#define EPSF 1e-8f

struct Top2 { float v0, v1; int i0, i1; };

// ---------------- 1 / ||descriptor|| per pixel -------------------------
__global__ void norm_kernel(const float* __restrict__ A,
                            const float* __restrict__ B,
                            float* __restrict__ rnA,
                            float* __restrict__ rnB) {
    int g = blockIdx.x * blockDim.x + threadIdx.x;   // 0..32767
    const float* X = (g < NP) ? A : B;
    float* o = (g < NP) ? rnA : rnB;
    int p = g & (NP - 1);
    float s = 0.f;
#pragma unroll 8
    for (int c = 0; c < CH; ++c) {
        float v = X[(size_t)c * NP + p];
        s = fmaf(v, v, s);
    }
    o[p] = 1.0f / sqrtf(s);
}

// ---------------- top-2 of (rnX[i]*rnY[j]*dot(X_i,Y_j)) per row ---------
// grid: 512 blocks = pass(2) x rowTile(128) x split(2)
__launch_bounds__(256, 2)
__global__ void top2_kernel(const float* __restrict__ A,
                            const float* __restrict__ B,
                            const float* __restrict__ rnA,
                            const float* __restrict__ rnB,
                            Top2* __restrict__ partials) {
    __shared__ __align__(16) float smem[2 * KC * LDX];
    float* Xs = smem;              // [KC][LDX]
    float* Ys = smem + KC * LDX;   // [KC][LDX]

    const int bid = blockIdx.x;
    const int pass = bid >> 8;            // 0: rows of sim, 1: rows of sim^T
    const int rowTile = (bid & 255) >> 1;
    const int split = bid & 1;

    const float* __restrict__ X = pass ? B : A;
    const float* __restrict__ Y = pass ? A : B;
    const float* __restrict__ rnX = pass ? rnB : rnA;
    const float* __restrict__ rnY = pass ? rnA : rnB;

    const int t = threadIdx.x;
    const int tx = t & 15;   // column group (16)
    const int ty = t >> 4;   // row group    (16)
    const int rowBase = rowTile * BM;

    float tv0[8], tv1[8];
    int ti0[8], ti1[8];
#pragma unroll
    for (int i = 0; i < 8; ++i) { tv0[i] = -3.f; tv1[i] = -3.f; ti0[i] = 0; ti1[i] = 0; }

    float rx[8];
#pragma unroll
    for (int i = 0; i < 8; ++i) rx[i] = rnX[rowBase + ty * 8 + i];

    for (int ct = 0; ct < CPS / BN; ++ct) {
        const int colBase = split * CPS + ct * BN;
        float acc[8][8];
#pragma unroll
        for (int i = 0; i < 8; ++i)
#pragma unroll
            for (int j = 0; j < 8; ++j) acc[i][j] = 0.f;

        for (int kc = 0; kc < CH; kc += KC) {
            __syncthreads();
            // stage KCxBM of X and Y as float4 (coalesced 512B per 32 lanes)
#pragma unroll
            for (int v = 0; v < 4; ++v) {
                int idx = t + v * 256;      // 0..1023
                int c = idx >> 5;           // 0..31
                int rq = idx & 31;          // float4 slot in row
                float4 xa = *(const float4*)(X + (size_t)(kc + c) * NP + rowBase + rq * 4);
                float4 yb = *(const float4*)(Y + (size_t)(kc + c) * NP + colBase + rq * 4);
                *(float4*)(Xs + c * LDX + rq * 4) = xa;
                *(float4*)(Ys + c * LDX + rq * 4) = yb;
            }
            __syncthreads();
#pragma unroll
            for (int c = 0; c < KC; ++c) {
                const float4 a0 = *(const float4*)(Xs + c * LDX + ty * 8);
                const float4 a1 = *(const float4*)(Xs + c * LDX + ty * 8 + 4);
                const float4 b0 = *(const float4*)(Ys + c * LDX + tx * 4);
                const float4 b1 = *(const float4*)(Ys + c * LDX + 64 + tx * 4);
                const float a[8] = {a0.x, a0.y, a0.z, a0.w, a1.x, a1.y, a1.z, a1.w};
                const float b[8] = {b0.x, b0.y, b0.z, b0.w, b1.x, b1.y, b1.z, b1.w};
#pragma unroll
                for (int i = 0; i < 8; ++i)
#pragma unroll
                    for (int j = 0; j < 8; ++j)
                        acc[i][j] = fmaf(a[i], b[j], acc[i][j]);
            }
        }
        // scale by norms, update running top-2 (8 rows x 8 cols per thread)
#pragma unroll
        for (int j = 0; j < 8; ++j) {
            const int col = colBase + ((j < 4) ? (tx * 4 + j) : (64 + tx * 4 + (j - 4)));
            const float ry = rnY[col];
#pragma unroll
            for (int i = 0; i < 8; ++i) {
                const float v = acc[i][j] * rx[i] * ry;
                if (v > tv1[i]) {
                    if (v > tv0[i]) { tv1[i] = tv0[i]; ti1[i] = ti0[i]; tv0[i] = v; ti0[i] = col; }
                    else            { tv1[i] = v; ti1[i] = col; }
                }
            }
        }
    }

    // merge top-2 across the 16 column-threads of each row (reuse LDS)
    __syncthreads();
    Top2* m = (Top2*)smem;  // [BM][16]
#pragma unroll
    for (int i = 0; i < 8; ++i) {
        Top2 p; p.v0 = tv0[i]; p.v1 = tv1[i]; p.i0 = ti0[i]; p.i1 = ti1[i];
        m[(ty * 8 + i) * 16 + tx] = p;
    }
    __syncthreads();
    if (t < BM) {
        float v0 = -4.f, v1 = -4.f; int i0 = 0, i1 = 0;
        for (int x = 0; x < 16; ++x) {
            Top2 p = m[t * 16 + x];
            if (p.v0 > v1) {
                if (p.v0 > v0) { v1 = v0; i1 = i0; v0 = p.v0; i0 = p.i0; }
                else           { v1 = p.v0; i1 = p.i0; }
            }
            if (p.v1 > v1) {
                if (p.v1 > v0) { v1 = v0; i1 = i0; v0 = p.v1; i0 = p.i1; }
                else           { v1 = p.v1; i1 = p.i1; }
            }
        }
        Top2 r; r.v0 = v0; r.v1 = v1; r.i0 = i0; r.i1 = i1;
        partials[(pass * NSPLIT + split) * NP + rowBase + t] = r;
    }
}

// ---------------- merge the 2 column-splits per (pass,row) --------------
__global__ void merge_kernel(const Top2* __restrict__ partials,
                             Top2* __restrict__ final12,
                             int* __restrict__ nn21,
                             float* __restrict__ ratio21) {
    int g = blockIdx.x * blockDim.x + threadIdx.x;  // 0..32767
    int pass = g >> 14;
    int row = g & (NP - 1);
    Top2 a = partials[(pass * NSPLIT + 0) * NP + row];
    Top2 b = partials[(pass * NSPLIT + 1) * NP + row];
    float v0 = a.v0, v1 = a.v1; int i0 = a.i0, i1 = a.i1;
    if (b.v0 > v1) {
        if (b.v0 > v0) { v1 = v0; i1 = i0; v0 = b.v0; i0 = b.i0; }
        else           { v1 = b.v0; i1 = b.i0; }
    }
    if (b.v1 > v1) {
        if (b.v1 > v0) { v1 = v0; i1 = i0; v0 = b.v1; i0 = b.i1; }
        else           { v1 = b.v1; i1 = b.i1; }
    }
    if (pass == 0) {
        Top2 r; r.v0 = v0; r.v1 = v1; r.i0 = i0; r.i1 = i1;
        final12[row] = r;
    } else {
        nn21[row] = i0;
        float d0 = sqrtf(fmaxf(2.f - 2.f * v0, 1e-12f));
        float d1 = sqrtf(fmaxf(2.f - 2.f * v1, 1e-12f));
        ratio21[row] = d0 / (d1 + EPSF);
    }
}

// ---------------- epilogue: mutual check, ratio test, border mask -------
__global__ void final_kernel(const Top2* __restrict__ final12,
                             const int* __restrict__ nn21,
                             const float* __restrict__ ratio21,
                             float* __restrict__ out) {
    int i = blockIdx.x * blockDim.x + threadIdx.x;  // 0..16383
    Top2 a = final12[i];
    float d0 = sqrtf(fmaxf(2.f - 2.f * a.v0, 1e-12f));
    float d1 = sqrtf(fmaxf(2.f - 2.f * a.v1, 1e-12f));
    int nn = a.i0;
    float r12 = d0 / (d1 + EPSF);
    bool mutual = (nn21[nn] == i);
    float r = fmaxf(r12, ratio21[nn]);
    int xA = i & (WDIM - 1), yA = i >> 7;
    int xB = nn & (WDIM - 1), yB = nn >> 7;
    bool border = (xA == 0) || (xA == WDIM - 1) || (yA == 0) || (yA == WDIM - 1) ||
                  (xB == 0) || (xB == WDIM - 1) || (yB == 0) || (yB == WDIM - 1);
    bool valid = mutual && (r < 0.95f) && !border;
    out[2 * i]     = valid ? d0 : 0.f;
    out[2 * i + 1] = valid ? d1 : 0.f;
    out[2 * NP + i] = (float)nn;
    out[3 * NP + i] = valid ? 1.f : 0.f;
}

extern "C" void kernel_launch(void* const* d_in, const int* in_sizes, int n_in,
                              void* d_out, int out_size, void* d_ws, size_t ws_size,
                              hipStream_t stream) {
    (void)in_sizes; (void)n_in; (void)out_size; (void)ws_size;
    const float* A = (const float*)d_in[0];
    const float* B = (const float*)d_in[1];
    float* out = (float*)d_out;

    char* ws = (char*)d_ws;
    float* rnA = (float*)ws;                    // 16384 f
    float* rnB = rnA + NP;                      // 16384 f
    Top2* partials = (Top2*)(rnB + NP);         // 4*16384 Top2 (1 MB)
    Top2* final12 = partials + 4 * NP;          // 16384 Top2
    int* nn21 = (int*)(final12 + NP);           // 16384 i
    float* ratio21 = (float*)(nn21 + NP);       // 16384 f

    norm_kernel<<<(2 * NP) / 256, 256, 0, stream>>>(A, B, rnA, rnB);
    top2_kernel<<<512, 256, 0, stream>>>(A, B, rnA, rnB, partials);
    merge_kernel<<<(2 * NP) / 256, 256, 0, stream>>>(partials, final12, nn21, ratio21);
    final_kernel<<<NP / 256, 256, 0, stream>>>(final12, nn21, ratio21, out);
}

// Round 2
// 514.125 us; speedup vs baseline: 6.6376x; 6.6376x over previous
//
#include <hip/hip_runtime.h>
#include <math.h>

#define NP 16384      // pixels per map (128*128)
#define CH 256        // channels (K)
#define WDIM 128
#define EPSF 1e-8f

#define TOPK 4
#define CHUNK 32              // cols per LDS chunk
#define SPLITS 4
#define COLS_PER_SPLIT (NP / SPLITS)       // 4096
#define NCHUNK (COLS_PER_SPLIT / CHUNK)    // 128
#define ROWS 256              // rows per block (4 waves x 64)
#define CHUNK_BYTES (CHUNK * CH * 2)       // 16384

typedef short short8 __attribute__((ext_vector_type(8)));
typedef float floatx4 __attribute__((ext_vector_type(4)));

typedef __attribute__((address_space(1))) const unsigned int gu32;
typedef __attribute__((address_space(3))) unsigned int lu32;

// ------------------------------------------------------------------
// prep: per-pixel 1/||d||, write fp32 normalized transposed [pix][256]
// and bf16 normalized swizzled (element ch stored at ch ^ ((pix&7)<<3))
// ------------------------------------------------------------------
__global__ __launch_bounds__(256) void prep_kernel(
    const float* __restrict__ A, const float* __restrict__ B,
    float* __restrict__ AT, float* __restrict__ BT,
    unsigned short* __restrict__ Abf, unsigned short* __restrict__ Bbf)
{
    __shared__ float tile[64 * 257];
    __shared__ float rnv[64];
    const int bid = blockIdx.x;
    const float* __restrict__ src = (bid < 256) ? A : B;
    float* __restrict__ dstT = (bid < 256) ? AT : BT;
    unsigned short* __restrict__ dstb = (bid < 256) ? Abf : Bbf;
    const int pixBase = (bid & 255) * 64;
    const int t = threadIdx.x;

    for (int k = 0; k < 64 * 256; k += 256) {
        int idx = k + t;
        int p = idx & 63;
        int c = idx >> 6;
        tile[p * 257 + c] = src[(size_t)c * NP + pixBase + p];
    }
    __syncthreads();
    if (t < 64) {
        float s = 0.f;
        for (int c = 0; c < 256; ++c) { float v = tile[t * 257 + c]; s = fmaf(v, v, s); }
        rnv[t] = 1.0f / sqrtf(s);
    }
    __syncthreads();
    // fp32 transposed normalized
    for (int k = 0; k < 64 * 256; k += 256) {
        int idx = k + t;
        int p = idx >> 8;
        int c = idx & 255;
        dstT[((size_t)(pixBase + p) << 8) + c] = tile[p * 257 + c] * rnv[p];
    }
    // bf16 swizzled normalized (write pairs)
    for (int k = 0; k < 64 * 128; k += 256) {
        int idx = k + t;
        int p = idx >> 7;
        int c2 = (idx & 127) * 2;
        float rn = rnv[p];
        float v0 = tile[p * 257 + c2] * rn;
        float v1 = tile[p * 257 + c2 + 1] * rn;
        unsigned u0 = __float_as_uint(v0); u0 = (u0 + 0x7fffu + ((u0 >> 16) & 1u)) >> 16;
        unsigned u1 = __float_as_uint(v1); u1 = (u1 + 0x7fffu + ((u1 >> 16) & 1u)) >> 16;
        unsigned sw = ((unsigned)(p & 7)) << 3;
        int e = ((pixBase + p) << 8) + (c2 ^ (int)sw);
        *(unsigned*)(dstb + e) = (u0 & 0xffffu) | (u1 << 16);
    }
}

// ------------------------------------------------------------------
// simk: bf16 MFMA sim sweep with per-lane running top-4 per row.
// grid 512: pass(2) x rowTile(64) x split(4). Block: 4 waves x 64 rows.
// Swapped operands: cols = M (A-operand), rows = N (B-operand, in regs).
// C frag: n(row-pixel) = lane&15, m(col-pixel) = (lane>>4)*4 + reg.
// ------------------------------------------------------------------
__global__ __launch_bounds__(256, 2) void simk_kernel(
    const unsigned short* __restrict__ Abf, const unsigned short* __restrict__ Bbf,
    int* __restrict__ cand)
{
    __shared__ __align__(16) char smem[2 * CHUNK_BYTES];  // 32 KB
    const int bid = blockIdx.x;
    const int pass = bid >> 8;
    const int rt = (bid >> 2) & 63;
    const int split = bid & 3;
    const unsigned short* __restrict__ rows_b = pass ? Bbf : Abf;
    const unsigned short* __restrict__ cols_b = pass ? Abf : Bbf;
    const int t = threadIdx.x;
    const int w = t >> 6;
    const int l = t & 63;
    const int l15 = l & 15, lhi = l >> 4;
    const int rowBase = rt * ROWS;
    const int colBase = split * COLS_PER_SPLIT;

    // --- preload row-descriptor fragments (B-operand): 4 ni x 8 kk ---
    short8 Bfr[4][8];
#pragma unroll
    for (int ni = 0; ni < 4; ++ni) {
        int pix = rowBase + w * 64 + ni * 16 + l15;
        const unsigned short* pr = rows_b + ((size_t)pix << 8);
        int sw = (pix & 7) << 3;
#pragma unroll
        for (int kk = 0; kk < 8; ++kk) {
            int ke = kk * 32 + lhi * 8;
            Bfr[ni][kk] = *(const short8*)(pr + (ke ^ sw));
        }
    }

    // --- precompute LDS byte offsets for A frags (mi=0; mi=1 is +8192) ---
    int aoff[8];
    {
        int cp = l15;                         // local col pixel 0..15
        int sw = (cp & 7) << 3;
#pragma unroll
        for (int kk = 0; kk < 8; ++kk) {
            int ke = kk * 32 + lhi * 8;
            aoff[kk] = (cp * 256 + (ke ^ sw)) * 2;
        }
    }

    float tv[4][TOPK]; int tc[4][TOPK];
#pragma unroll
    for (int ni = 0; ni < 4; ++ni)
#pragma unroll
        for (int s = 0; s < TOPK; ++s) { tv[ni][s] = -2.f; tc[ni][s] = 0; }

    const char* gbase = (const char*)(cols_b + ((size_t)colBase << 8));

    // stage chunk 0
#pragma unroll
    for (int r = 0; r < 4; ++r) {
        int off = w * 4096 + r * 1024;
        __builtin_amdgcn_global_load_lds((gu32*)(gbase + off + l * 16),
                                         (lu32*)(smem + off), 16, 0, 0);
    }
    __syncthreads();

    for (int c = 0; c < NCHUNK; ++c) {
        // stage next chunk (clamped; overlapped with compute, drained by syncthreads)
        int nc = (c + 1 < NCHUNK) ? (c + 1) : c;
        const char* gn = gbase + (size_t)nc * CHUNK_BYTES;
        char* bufn = smem + ((c + 1) & 1) * CHUNK_BYTES;
#pragma unroll
        for (int r = 0; r < 4; ++r) {
            int off = w * 4096 + r * 1024;
            __builtin_amdgcn_global_load_lds((gu32*)(gn + off + l * 16),
                                             (lu32*)(bufn + off), 16, 0, 0);
        }

        const char* buf = smem + (c & 1) * CHUNK_BYTES;
        floatx4 acc[2][4];
#pragma unroll
        for (int mi = 0; mi < 2; ++mi)
#pragma unroll
            for (int ni = 0; ni < 4; ++ni) {
                floatx4 z = {0.f, 0.f, 0.f, 0.f};
                acc[mi][ni] = z;
            }
#pragma unroll
        for (int kk = 0; kk < 8; ++kk) {
            short8 a0 = *(const short8*)(buf + aoff[kk]);
            short8 a1 = *(const short8*)(buf + aoff[kk] + 8192);
#pragma unroll
            for (int ni = 0; ni < 4; ++ni) {
                acc[0][ni] = __builtin_amdgcn_mfma_f32_16x16x32_bf16(a0, Bfr[ni][kk], acc[0][ni], 0, 0, 0);
                acc[1][ni] = __builtin_amdgcn_mfma_f32_16x16x32_bf16(a1, Bfr[ni][kk], acc[1][ni], 0, 0, 0);
            }
        }
        // top-K update: per lane 4 rows x 8 cols
        int colC = colBase + c * CHUNK + lhi * 4;
#pragma unroll
        for (int mi = 0; mi < 2; ++mi) {
#pragma unroll
            for (int reg = 0; reg < 4; ++reg) {
                int col = colC + mi * 16 + reg;
#pragma unroll
                for (int ni = 0; ni < 4; ++ni) {
                    float v = acc[mi][ni][reg];
                    if (v > tv[ni][TOPK - 1]) {
                        float nv = v; int ncd = col;
#pragma unroll
                        for (int s = 0; s < TOPK; ++s) {
                            if (nv > tv[ni][s]) {
                                float fv = tv[ni][s]; int fc = tc[ni][s];
                                tv[ni][s] = nv; tc[ni][s] = ncd;
                                nv = fv; ncd = fc;
                            }
                        }
                    }
                }
            }
        }
        __syncthreads();
    }

    // --- merge per row: 4 lanes x TOPK -> top-6 per split, via LDS ---
    int2* mrg = (int2*)smem;   // [256 rows][4 slots][TOPK] = 32 KB
#pragma unroll
    for (int ni = 0; ni < 4; ++ni) {
        int rloc = w * 64 + ni * 16 + l15;
#pragma unroll
        for (int s = 0; s < TOPK; ++s) {
            int2 p; p.x = __float_as_int(tv[ni][s]); p.y = tc[ni][s];
            mrg[(rloc * 4 + lhi) * TOPK + s] = p;
        }
    }
    __syncthreads();
    {
        float bv[6]; int bc[6];
#pragma unroll
        for (int s = 0; s < 6; ++s) { bv[s] = -3.f; bc[s] = 0; }
        for (int j = 0; j < 4 * TOPK; ++j) {
            int2 p = mrg[t * 4 * TOPK + j];
            float v = __int_as_float(p.x);
            if (v > bv[5]) {
                float nv = v; int ncd = p.y;
#pragma unroll
                for (int s = 0; s < 6; ++s) {
                    if (nv > bv[s]) {
                        float fv = bv[s]; int fc = bc[s];
                        bv[s] = nv; bc[s] = ncd; nv = fv; ncd = fc;
                    }
                }
            }
        }
        int rowG = rowBase + t;
        int* o = cand + ((size_t)(pass * NP + rowG)) * 24 + split * 6;
#pragma unroll
        for (int s = 0; s < 6; ++s) o[s] = bc[s];
    }
}

// ------------------------------------------------------------------
// rescore: exact fp32 top-2 over 24 candidates per row (wave per row)
// ------------------------------------------------------------------
__global__ __launch_bounds__(256) void rescore_kernel(
    const float* __restrict__ AT, const float* __restrict__ BT,
    const int* __restrict__ cand,
    float4* __restrict__ final12,
    int* __restrict__ nn21, float* __restrict__ ratio21)
{
    const int t = threadIdx.x;
    const int w = t >> 6, l = t & 63;
    const int g = blockIdx.x * 4 + w;      // 0..32767
    const int pass = g >> 14;
    const int row = g & (NP - 1);
    const float* __restrict__ rT = pass ? BT : AT;
    const float* __restrict__ cT = pass ? AT : BT;
    float4 rv = *(const float4*)(rT + ((size_t)row << 8) + l * 4);
    float v0 = -4.f, v1 = -4.f; int i0 = 0x7fffffff, i1 = 0x7fffffff;
    const int* __restrict__ cl = cand + (size_t)g * 24;
#pragma unroll 4
    for (int j = 0; j < 24; ++j) {
        int idx = cl[j];
        float4 cv = *(const float4*)(cT + ((size_t)idx << 8) + l * 4);
        float d = rv.x * cv.x;
        d = fmaf(rv.y, cv.y, d);
        d = fmaf(rv.z, cv.z, d);
        d = fmaf(rv.w, cv.w, d);
#pragma unroll
        for (int m = 1; m < 64; m <<= 1) d += __shfl_xor(d, m, 64);
        // top-2 with lowest-index tie-break (top_k semantics)
        if (d > v0 || (d == v0 && idx < i0)) {
            v1 = v0; i1 = i0; v0 = d; i0 = idx;
        } else if (d > v1 || (d == v1 && idx < i1)) {
            v1 = d; i1 = idx;
        }
    }
    if (l == 0) {
        if (pass == 0) {
            float4 r; r.x = v0; r.y = v1;
            r.z = __int_as_float(i0); r.w = __int_as_float(i1);
            final12[row] = r;
        } else {
            nn21[row] = i0;
            float d0 = sqrtf(fmaxf(2.f - 2.f * v0, 1e-12f));
            float d1 = sqrtf(fmaxf(2.f - 2.f * v1, 1e-12f));
            ratio21[row] = d0 / (d1 + EPSF);
        }
    }
}

// ------------------------------------------------------------------
// final: mutual check, ratio test, border mask
// ------------------------------------------------------------------
__global__ void final_kernel(const float4* __restrict__ final12,
                             const int* __restrict__ nn21,
                             const float* __restrict__ ratio21,
                             float* __restrict__ out) {
    int i = blockIdx.x * blockDim.x + threadIdx.x;  // 0..16383
    float4 a = final12[i];
    float d0 = sqrtf(fmaxf(2.f - 2.f * a.x, 1e-12f));
    float d1 = sqrtf(fmaxf(2.f - 2.f * a.y, 1e-12f));
    int nn = __float_as_int(a.z);
    float r12 = d0 / (d1 + EPSF);
    bool mutual = (nn21[nn] == i);
    float r = fmaxf(r12, ratio21[nn]);
    int xA = i & (WDIM - 1), yA = i >> 7;
    int xB = nn & (WDIM - 1), yB = nn >> 7;
    bool border = (xA == 0) || (xA == WDIM - 1) || (yA == 0) || (yA == WDIM - 1) ||
                  (xB == 0) || (xB == WDIM - 1) || (yB == 0) || (yB == WDIM - 1);
    bool valid = mutual && (r < 0.95f) && !border;
    out[2 * i]       = valid ? d0 : 0.f;
    out[2 * i + 1]   = valid ? d1 : 0.f;
    out[2 * NP + i]  = (float)nn;
    out[3 * NP + i]  = valid ? 1.f : 0.f;
}

extern "C" void kernel_launch(void* const* d_in, const int* in_sizes, int n_in,
                              void* d_out, int out_size, void* d_ws, size_t ws_size,
                              hipStream_t stream) {
    (void)in_sizes; (void)n_in; (void)out_size; (void)ws_size;
    const float* A = (const float*)d_in[0];
    const float* B = (const float*)d_in[1];
    float* out = (float*)d_out;

    char* ws = (char*)d_ws;
    float* AT = (float*)ws;                              // 16 MB
    float* BT = AT + (size_t)NP * CH;                    // 16 MB
    unsigned short* Abf = (unsigned short*)(BT + (size_t)NP * CH);   // 8 MB
    unsigned short* Bbf = Abf + (size_t)NP * CH;                     // 8 MB
    int* cand = (int*)(Bbf + (size_t)NP * CH);           // 2*NP*24*4 = 3 MB
    float4* final12 = (float4*)(cand + (size_t)2 * NP * 24);  // 256 KB
    int* nn21 = (int*)(final12 + NP);                    // 64 KB
    float* ratio21 = (float*)(nn21 + NP);                // 64 KB

    prep_kernel<<<512, 256, 0, stream>>>(A, B, AT, BT, Abf, Bbf);
    simk_kernel<<<512, 256, 0, stream>>>(Abf, Bbf, cand);
    rescore_kernel<<<8192, 256, 0, stream>>>(AT, BT, cand, final12, nn21, ratio21);
    final_kernel<<<NP / 256, 256, 0, stream>>>(final12, nn21, ratio21, out);
}

// Round 3
// 376.424 us; speedup vs baseline: 9.0657x; 1.3658x over previous
//
#include <hip/hip_runtime.h>
#include <math.h>

#define NP 16384      // pixels per map (128*128)
#define CH 256        // channels (K)
#define WDIM 128
#define EPSF 1e-8f

#define TOPK 4
#define CHUNK 32              // cols per LDS chunk
#define SPLITS 4
#define COLS_PER_SPLIT (NP / SPLITS)       // 4096
#define NCHUNK (COLS_PER_SPLIT / CHUNK)    // 128
#define ROWS 256              // rows per block (4 waves x 64)
#define CHUNK_BYTES (CHUNK * CH * 2)       // 16384

typedef short short8 __attribute__((ext_vector_type(8)));
typedef float floatx4 __attribute__((ext_vector_type(4)));

typedef __attribute__((address_space(1))) const unsigned int gu32;
typedef __attribute__((address_space(3))) unsigned int lu32;

#define NEG_INF_F __int_as_float(0xFF800000)

// ------------------------------------------------------------------
// prep: per-pixel 1/||d||, write fp32 normalized transposed [pix][256]
// and bf16 normalized swizzled (element ch stored at ch ^ ((pix&7)<<3))
// ------------------------------------------------------------------
__global__ __launch_bounds__(256) void prep_kernel(
    const float* __restrict__ A, const float* __restrict__ B,
    float* __restrict__ AT, float* __restrict__ BT,
    unsigned short* __restrict__ Abf, unsigned short* __restrict__ Bbf)
{
    __shared__ float tile[64 * 257];
    __shared__ float rnv[64];
    const int bid = blockIdx.x;
    const float* __restrict__ src = (bid < 256) ? A : B;
    float* __restrict__ dstT = (bid < 256) ? AT : BT;
    unsigned short* __restrict__ dstb = (bid < 256) ? Abf : Bbf;
    const int pixBase = (bid & 255) * 64;
    const int t = threadIdx.x;

    for (int k = 0; k < 64 * 256; k += 256) {
        int idx = k + t;
        int p = idx & 63;
        int c = idx >> 6;
        tile[p * 257 + c] = src[(size_t)c * NP + pixBase + p];
    }
    __syncthreads();
    if (t < 64) {
        float s = 0.f;
        for (int c = 0; c < 256; ++c) { float v = tile[t * 257 + c]; s = fmaf(v, v, s); }
        rnv[t] = 1.0f / sqrtf(s);
    }
    __syncthreads();
    // fp32 transposed normalized
    for (int k = 0; k < 64 * 256; k += 256) {
        int idx = k + t;
        int p = idx >> 8;
        int c = idx & 255;
        dstT[((size_t)(pixBase + p) << 8) + c] = tile[p * 257 + c] * rnv[p];
    }
    // bf16 swizzled normalized (write pairs)
    for (int k = 0; k < 64 * 128; k += 256) {
        int idx = k + t;
        int p = idx >> 7;
        int c2 = (idx & 127) * 2;
        float rn = rnv[p];
        float v0 = tile[p * 257 + c2] * rn;
        float v1 = tile[p * 257 + c2 + 1] * rn;
        unsigned u0 = __float_as_uint(v0); u0 = (u0 + 0x7fffu + ((u0 >> 16) & 1u)) >> 16;
        unsigned u1 = __float_as_uint(v1); u1 = (u1 + 0x7fffu + ((u1 >> 16) & 1u)) >> 16;
        unsigned sw = ((unsigned)(p & 7)) << 3;
        int e = ((pixBase + p) << 8) + (c2 ^ (int)sw);
        *(unsigned*)(dstb + e) = (u0 & 0xffffu) | (u1 << 16);
    }
}

// ------------------------------------------------------------------
// simk: bf16 MFMA sim sweep, packed-key branchless per-lane top-4.
// grid 512: pass(2) x rowTile(64) x split(4). Block: 4 waves x 64 rows.
// Swapped operands: cols = M (A-operand), rows = N (B-operand, in regs).
// key = (sim_bits & 0xFFFFF000) | col_local(12b); float-orderable.
// ------------------------------------------------------------------
__global__ __launch_bounds__(256, 2) void simk_kernel(
    const unsigned short* __restrict__ Abf, const unsigned short* __restrict__ Bbf,
    int* __restrict__ cand)
{
    __shared__ __align__(16) char smem[2 * CHUNK_BYTES];  // 32 KB
    const int bid = blockIdx.x;
    const int pass = bid >> 8;
    const int rt = (bid >> 2) & 63;
    const int split = bid & 3;
    const unsigned short* __restrict__ rows_b = pass ? Bbf : Abf;
    const unsigned short* __restrict__ cols_b = pass ? Abf : Bbf;
    const int t = threadIdx.x;
    const int w = t >> 6;
    const int l = t & 63;
    const int l15 = l & 15, lhi = l >> 4;
    const int rowBase = rt * ROWS;
    const int colBase = split * COLS_PER_SPLIT;

    // --- preload row-descriptor fragments (B-operand): 4 ni x 8 kk ---
    short8 Bfr[4][8];
#pragma unroll
    for (int ni = 0; ni < 4; ++ni) {
        int pix = rowBase + w * 64 + ni * 16 + l15;
        const unsigned short* pr = rows_b + ((size_t)pix << 8);
        int sw = (pix & 7) << 3;
#pragma unroll
        for (int kk = 0; kk < 8; ++kk) {
            int ke = kk * 32 + lhi * 8;
            Bfr[ni][kk] = *(const short8*)(pr + (ke ^ sw));
        }
    }
    // pin Bfr in registers: loads may not be rematerialized across a clobber
    asm volatile("" ::: "memory");

    // --- precompute LDS byte offsets for A frags (mi=0; mi=1 is +8192) ---
    int aoff[8];
    {
        int cp = l15;
        int sw = (cp & 7) << 3;
#pragma unroll
        for (int kk = 0; kk < 8; ++kk) {
            int ke = kk * 32 + lhi * 8;
            aoff[kk] = (cp * 256 + (ke ^ sw)) * 2;
        }
    }

    // per-(mi,reg) low index bits: lhi*4 + mi*16 + reg  (low 5 bits of col)
    int idxbase[2][4];
#pragma unroll
    for (int mi = 0; mi < 2; ++mi)
#pragma unroll
        for (int reg = 0; reg < 4; ++reg)
            idxbase[mi][reg] = lhi * 4 + mi * 16 + reg;

    // packed-key top-4, sorted descending
    float tv[4][TOPK];
#pragma unroll
    for (int ni = 0; ni < 4; ++ni)
#pragma unroll
        for (int s = 0; s < TOPK; ++s) tv[ni][s] = NEG_INF_F;

    const char* gbase = (const char*)(cols_b + ((size_t)colBase << 8));
    const floatx4 fzero = {0.f, 0.f, 0.f, 0.f};

    // stage chunk 0
#pragma unroll
    for (int r = 0; r < 4; ++r) {
        int off = w * 4096 + r * 1024;
        __builtin_amdgcn_global_load_lds((gu32*)(gbase + off + l * 16),
                                         (lu32*)(smem + off), 16, 0, 0);
    }
    __syncthreads();

    for (int c = 0; c < NCHUNK; ++c) {
        // stage next chunk (drained by the end-of-chunk barrier)
        int nc = (c + 1 < NCHUNK) ? (c + 1) : c;
        const char* gn = gbase + (size_t)nc * CHUNK_BYTES;
        char* bufn = smem + ((c + 1) & 1) * CHUNK_BYTES;
#pragma unroll
        for (int r = 0; r < 4; ++r) {
            int off = w * 4096 + r * 1024;
            __builtin_amdgcn_global_load_lds((gu32*)(gn + off + l * 16),
                                             (lu32*)(bufn + off), 16, 0, 0);
        }

        const char* buf = smem + (c & 1) * CHUNK_BYTES;
        floatx4 acc[2][4];
        // kk = 0 peeled: accumulate from hoisted zero (no acc init movs)
        {
            short8 a0 = *(const short8*)(buf + aoff[0]);
            short8 a1 = *(const short8*)(buf + aoff[0] + 8192);
#pragma unroll
            for (int ni = 0; ni < 4; ++ni) {
                acc[0][ni] = __builtin_amdgcn_mfma_f32_16x16x32_bf16(a0, Bfr[ni][0], fzero, 0, 0, 0);
                acc[1][ni] = __builtin_amdgcn_mfma_f32_16x16x32_bf16(a1, Bfr[ni][0], fzero, 0, 0, 0);
            }
        }
#pragma unroll
        for (int kk = 1; kk < 8; ++kk) {
            short8 a0 = *(const short8*)(buf + aoff[kk]);
            short8 a1 = *(const short8*)(buf + aoff[kk] + 8192);
#pragma unroll
            for (int ni = 0; ni < 4; ++ni) {
                acc[0][ni] = __builtin_amdgcn_mfma_f32_16x16x32_bf16(a0, Bfr[ni][kk], acc[0][ni], 0, 0, 0);
                acc[1][ni] = __builtin_amdgcn_mfma_f32_16x16x32_bf16(a1, Bfr[ni][kk], acc[1][ni], 0, 0, 0);
            }
        }

        // packed-key branchless top-4: 8 VALU per value
        const int cS = c << 5;
#pragma unroll
        for (int mi = 0; mi < 2; ++mi) {
#pragma unroll
            for (int reg = 0; reg < 4; ++reg) {
                const int ib = idxbase[mi][reg] | cS;
#pragma unroll
                for (int ni = 0; ni < 4; ++ni) {
                    int kbits = (__float_as_int(acc[mi][ni][reg]) & 0xFFFFF000) | ib;
                    float fk = __int_as_float(kbits);
                    float h;
                    h = fmaxf(tv[ni][0], fk); fk = fminf(tv[ni][0], fk); tv[ni][0] = h;
                    h = fmaxf(tv[ni][1], fk); fk = fminf(tv[ni][1], fk); tv[ni][1] = h;
                    h = fmaxf(tv[ni][2], fk); fk = fminf(tv[ni][2], fk); tv[ni][2] = h;
                    tv[ni][3] = fmaxf(tv[ni][3], fk);
                }
            }
        }
        __syncthreads();
    }

    // --- merge per row: 4 lanes x top4 packed keys -> top-6 per split ---
    int4* mrg = (int4*)smem;   // [256 rows][4 lhi] int4 = 16 KB
#pragma unroll
    for (int ni = 0; ni < 4; ++ni) {
        int rloc = w * 64 + ni * 16 + l15;
        int4 p;
        p.x = __float_as_int(tv[ni][0]);
        p.y = __float_as_int(tv[ni][1]);
        p.z = __float_as_int(tv[ni][2]);
        p.w = __float_as_int(tv[ni][3]);
        mrg[rloc * 4 + lhi] = p;
    }
    __syncthreads();
    {
        float bv[6];
#pragma unroll
        for (int s = 0; s < 6; ++s) bv[s] = NEG_INF_F;
        for (int q = 0; q < 4; ++q) {
            int4 p = mrg[t * 4 + q];
            int ks[4] = {p.x, p.y, p.z, p.w};
#pragma unroll
            for (int j = 0; j < 4; ++j) {
                float fk = __int_as_float(ks[j]);
                float h;
#pragma unroll
                for (int s = 0; s < 6; ++s) {
                    h = fmaxf(bv[s], fk); fk = fminf(bv[s], fk); bv[s] = h;
                }
            }
        }
        int rowG = rowBase + t;
        int* o = cand + ((size_t)(pass * NP + rowG)) * 24 + split * 6;
#pragma unroll
        for (int s = 0; s < 6; ++s)
            o[s] = colBase + (__float_as_int(bv[s]) & 0xFFF);
    }
}

// ------------------------------------------------------------------
// rescore: exact fp32 top-2 over 24 candidates per row (wave per row)
// ------------------------------------------------------------------
__global__ __launch_bounds__(256) void rescore_kernel(
    const float* __restrict__ AT, const float* __restrict__ BT,
    const int* __restrict__ cand,
    float4* __restrict__ final12,
    int* __restrict__ nn21, float* __restrict__ ratio21)
{
    const int t = threadIdx.x;
    const int w = t >> 6, l = t & 63;
    const int g = blockIdx.x * 4 + w;      // 0..32767
    const int pass = g >> 14;
    const int row = g & (NP - 1);
    const float* __restrict__ rT = pass ? BT : AT;
    const float* __restrict__ cT = pass ? AT : BT;
    float4 rv = *(const float4*)(rT + ((size_t)row << 8) + l * 4);
    float v0 = -4.f, v1 = -4.f; int i0 = 0x7fffffff, i1 = 0x7fffffff;
    const int* __restrict__ cl = cand + (size_t)g * 24;
#pragma unroll 4
    for (int j = 0; j < 24; ++j) {
        int idx = cl[j];
        float4 cv = *(const float4*)(cT + ((size_t)idx << 8) + l * 4);
        float d = rv.x * cv.x;
        d = fmaf(rv.y, cv.y, d);
        d = fmaf(rv.z, cv.z, d);
        d = fmaf(rv.w, cv.w, d);
#pragma unroll
        for (int m = 1; m < 64; m <<= 1) d += __shfl_xor(d, m, 64);
        // top-2 with lowest-index tie-break (top_k semantics)
        if (d > v0 || (d == v0 && idx < i0)) {
            v1 = v0; i1 = i0; v0 = d; i0 = idx;
        } else if (d > v1 || (d == v1 && idx < i1)) {
            v1 = d; i1 = idx;
        }
    }
    if (l == 0) {
        if (pass == 0) {
            float4 r; r.x = v0; r.y = v1;
            r.z = __int_as_float(i0); r.w = __int_as_float(i1);
            final12[row] = r;
        } else {
            nn21[row] = i0;
            float d0 = sqrtf(fmaxf(2.f - 2.f * v0, 1e-12f));
            float d1 = sqrtf(fmaxf(2.f - 2.f * v1, 1e-12f));
            ratio21[row] = d0 / (d1 + EPSF);
        }
    }
}

// ------------------------------------------------------------------
// final: mutual check, ratio test, border mask
// ------------------------------------------------------------------
__global__ void final_kernel(const float4* __restrict__ final12,
                             const int* __restrict__ nn21,
                             const float* __restrict__ ratio21,
                             float* __restrict__ out) {
    int i = blockIdx.x * blockDim.x + threadIdx.x;  // 0..16383
    float4 a = final12[i];
    float d0 = sqrtf(fmaxf(2.f - 2.f * a.x, 1e-12f));
    float d1 = sqrtf(fmaxf(2.f - 2.f * a.y, 1e-12f));
    int nn = __float_as_int(a.z);
    float r12 = d0 / (d1 + EPSF);
    bool mutual = (nn21[nn] == i);
    float r = fmaxf(r12, ratio21[nn]);
    int xA = i & (WDIM - 1), yA = i >> 7;
    int xB = nn & (WDIM - 1), yB = nn >> 7;
    bool border = (xA == 0) || (xA == WDIM - 1) || (yA == 0) || (yA == WDIM - 1) ||
                  (xB == 0) || (xB == WDIM - 1) || (yB == 0) || (yB == WDIM - 1);
    bool valid = mutual && (r < 0.95f) && !border;
    out[2 * i]       = valid ? d0 : 0.f;
    out[2 * i + 1]   = valid ? d1 : 0.f;
    out[2 * NP + i]  = (float)nn;
    out[3 * NP + i]  = valid ? 1.f : 0.f;
}

extern "C" void kernel_launch(void* const* d_in, const int* in_sizes, int n_in,
                              void* d_out, int out_size, void* d_ws, size_t ws_size,
                              hipStream_t stream) {
    (void)in_sizes; (void)n_in; (void)out_size; (void)ws_size;
    const float* A = (const float*)d_in[0];
    const float* B = (const float*)d_in[1];
    float* out = (float*)d_out;

    char* ws = (char*)d_ws;
    float* AT = (float*)ws;                              // 16 MB
    float* BT = AT + (size_t)NP * CH;                    // 16 MB
    unsigned short* Abf = (unsigned short*)(BT + (size_t)NP * CH);   // 8 MB
    unsigned short* Bbf = Abf + (size_t)NP * CH;                     // 8 MB
    int* cand = (int*)(Bbf + (size_t)NP * CH);           // 2*NP*24*4 = 3 MB
    float4* final12 = (float4*)(cand + (size_t)2 * NP * 24);  // 256 KB
    int* nn21 = (int*)(final12 + NP);                    // 64 KB
    float* ratio21 = (float*)(nn21 + NP);                // 64 KB

    prep_kernel<<<512, 256, 0, stream>>>(A, B, AT, BT, Abf, Bbf);
    simk_kernel<<<512, 256, 0, stream>>>(Abf, Bbf, cand);
    rescore_kernel<<<8192, 256, 0, stream>>>(AT, BT, cand, final12, nn21, ratio21);
    final_kernel<<<NP / 256, 256, 0, stream>>>(final12, nn21, ratio21, out);
}